// Round 6
// baseline (204.702 us; speedup 1.0000x reference)
//
#include <hip/hip_runtime.h>

#define BB 4
#define CC 256
#define HH 96
#define WW 128
#define PP 9
#define OFF 4
#define CG 2             // channel groups inside one block
#define CPB (CC / CG)    // 128 channels per group
#define CCH 16           // channels per chunk
#define NPAIR (CCH / 2)  // 8 f16x2 channel pairs per chunk
#define NCH (CPB / CCH)  // 8 chunks per group
#define TPB 576          // 2 cg * 9 dy * 32 pxg = 9 full waves
#define TW 72            // staged in2 cols (64 out + 8 halo)
#define XCOLS 64         // output columns per block

typedef _Float16 h2 __attribute__((ext_vector_type(2)));

__device__ __forceinline__ h2 u2h(unsigned u) { union { unsigned u; h2 h; } x; x.u = u; return x.h; }

#if __has_builtin(__builtin_amdgcn_fdot2)
__device__ __forceinline__ float dot2(h2 a, h2 b, float c) { return __builtin_amdgcn_fdot2(a, b, c, false); }
#else
__device__ __forceinline__ float dot2(h2 a, h2 b, float c) { return c + (float)a[0] * (float)b[0] + (float)a[1] * (float)b[1]; }
#endif

__device__ __forceinline__ unsigned pk(float a, float b) {
#if __has_builtin(__builtin_amdgcn_cvt_pkrtz)
  auto r = __builtin_amdgcn_cvt_pkrtz(a, b);
  unsigned u; __builtin_memcpy(&u, &r, 4); return u;
#else
  h2 h; h[0] = (_Float16)a; h[1] = (_Float16)b;
  unsigned u; __builtin_memcpy(&u, &h, 4); return u;
#endif
}

// 768 blocks (4b*96h*2xh) x 9 full waves = 3 blocks/CU, 27 waves/CU (84% occ).
// Channel dim split across two in-block groups (separate LDS tiles), reduced
// once through LDS at the end. Global loads for chunk c+1 prefetched into
// registers during compute of chunk c (R5's pipeline, kept).
__global__ __launch_bounds__(TPB, 7) void corr_kernel(const float* __restrict__ in1,
                                                      const float* __restrict__ in2,
                                                      float* __restrict__ out) {
  __shared__ unsigned s2[CG][NPAIR][PP][TW];   // 41472 B
  __shared__ unsigned s1[CG][NPAIR][XCOLS];    // 4096 B -> 45.6 KB, 3 blocks/CU

  // XCD swizzle: 12-row h-band per XCD so the 9-row dy-halo stays in-XCD L2.
  const int bx = blockIdx.x;
  const int xcd = bx & 7;
  const int slot = bx >> 3;            // 0..95
  const int xh = slot & 1;
  const int s3 = slot >> 1;            // 0..47
  const int b = s3 / 12;
  const int h = xcd * 12 + (s3 % 12);
  const int xbase = xh * XCOLS;

  const int tid = threadIdx.x;
  const int cg = (tid >= 288) ? 1 : 0; // channel group
  const int ltid = tid - 288 * cg;     // 0..287 within group
  const int dy = ltid >> 5;            // 0..8
  const int pxg = ltid & 31;           // 0..31
  const int L0 = pxg << 1;             // 2 output px -> lds cols L0, L0+1

  // staging role: 288 = 8 pairs * 36 col-pairs; edge pairs are fully OOB,
  // so column validity is one per-lane bool; row validity is block-uniform.
  const int sp = ltid / 36;            // channel pair 0..7
  const int sc2 = ltid - sp * 36;      // col-pair 0..35
  const int sL = sc2 << 1;
  const int sgx = xbase - OFF + sL;    // global x of staged pair (even)
  const bool colv = (sgx >= 0) && (sgx < WW);
  const int rlo = (h >= OFF) ? 0 : (OFF - h);
  const int rhi = (PP < HH + OFF - h) ? PP : (HH + OFF - h);

  const int plane = HH * WW;           // 12288
  const long base_b = (long)b * CC * plane;

  // hoisted base pointers (advance by CCH*plane per chunk)
  const float* p2a = in2 + base_b + (long)(cg * CPB + 2 * sp) * plane + (long)(h - OFF) * WW + sgx;
  const float* p2b = p2a + plane;
  const int i1p = ltid >> 5, i1c = ltid & 31;  // in1 role (ltid<256)
  const float* p1a = in1 + base_b + (long)(cg * CPB + 2 * i1p) * plane + h * WW + xbase + (i1c << 1);
  const float* p1b = p1a + plane;
  const bool in1v = (ltid < NPAIR * 32);

  // pre-zero s2 once: OOB rows/cols never written afterwards
  for (int i = tid; i < CG * NPAIR * PP * TW; i += TPB) ((unsigned*)s2)[i] = 0u;

  float acc[2][PP];
#pragma unroll
  for (int px = 0; px < 2; ++px)
#pragma unroll
    for (int dx = 0; dx < PP; ++dx) acc[px][dx] = 0.f;

  float2 fa[PP], fb[PP], ga, gb;

  // ---- prefetch chunk 0
  if (colv) {
#pragma unroll
    for (int r = 0; r < PP; ++r)
      if (r >= rlo && r < rhi) {
        fa[r] = *(const float2*)(p2a + r * WW);
        fb[r] = *(const float2*)(p2b + r * WW);
      }
  }
  if (in1v) { ga = *(const float2*)p1a; gb = *(const float2*)p1b; }
  __syncthreads();  // covers the pre-zero

#pragma unroll 1
  for (int c = 0; c < NCH; ++c) {
    // ---- store phase: pk prefetched regs -> LDS
    if (colv) {
#pragma unroll
      for (int r = 0; r < PP; ++r)
        if (r >= rlo && r < rhi)
          *(uint2*)&s2[cg][sp][r][sL] = make_uint2(pk(fa[r].x, fb[r].x), pk(fa[r].y, fb[r].y));
    }
    if (in1v)
      *(uint2*)&s1[cg][i1p][i1c << 1] = make_uint2(pk(ga.x, gb.x), pk(ga.y, gb.y));
    __syncthreads();  // A: LDS visible

    // ---- prefetch chunk c+1 (in flight during compute)
    if (c + 1 < NCH) {
      const long adv = (long)(c + 1) * CCH * plane;
      if (colv) {
#pragma unroll
        for (int r = 0; r < PP; ++r)
          if (r >= rlo && r < rhi) {
            fa[r] = *(const float2*)(p2a + adv + r * WW);
            fb[r] = *(const float2*)(p2b + adv + r * WW);
          }
      }
      if (in1v) { ga = *(const float2*)(p1a + adv); gb = *(const float2*)(p1b + adv); }
    }

    // ---- compute chunk c: 2px x 9dx sliding f16x2 window
#pragma unroll
    for (int p = 0; p < NPAIR; ++p) {
      unsigned q[2], w[10];
      *(uint2*)q = *(const uint2*)&s1[cg][p][L0];
#pragma unroll
      for (int i = 0; i < 5; ++i)
        *(uint2*)&w[2 * i] = *(const uint2*)&s2[cg][p][dy][L0 + 2 * i];
#pragma unroll
      for (int px = 0; px < 2; ++px)
#pragma unroll
        for (int dx = 0; dx < PP; ++dx)
          acc[px][dx] = dot2(u2h(w[px + dx]), u2h(q[px]), acc[px][dx]);
    }
    __syncthreads();  // B: s2/s1 reads done before next overwrite
  }

  // ---- cross-group reduction through dead s2 space (all reads drained at B)
  float2* red = (float2*)s2;  // 288 * 9 float2 = 20736 B < 41472 B
  if (cg) {
#pragma unroll
    for (int dx = 0; dx < PP; ++dx)
      red[ltid * PP + dx] = make_float2(acc[0][dx], acc[1][dx]);
  }
  __syncthreads();
  if (!cg) {
    const int gx0 = xbase + L0;
    float* ob = out + ((long)(b * PP + dy) * PP) * plane + h * WW + gx0;
#pragma unroll
    for (int dx = 0; dx < PP; ++dx) {
      const float2 v = red[ltid * PP + dx];
      *(float2*)(ob + (long)dx * plane) = make_float2(acc[0][dx] + v.x, acc[1][dx] + v.y);
    }
  }
}

extern "C" void kernel_launch(void* const* d_in, const int* in_sizes, int n_in,
                              void* d_out, int out_size, void* d_ws, size_t ws_size,
                              hipStream_t stream) {
  const float* in1 = (const float*)d_in[0];
  const float* in2 = (const float*)d_in[1];
  float* out = (float*)d_out;
  // 768 blocks = 4b * 96h * 2xh (xcd-swizzled), 576 thr = 2cg * 9dy * 32pxg
  corr_kernel<<<dim3(BB * HH * 2), dim3(TPB), 0, stream>>>(in1, in2, out);
}